// Round 8
// baseline (165.260 us; speedup 1.0000x reference)
//
#include <hip/hip_runtime.h>
#include <math.h>

#define B_TOT 2048
#define D_INC 15
#define KW    40
#define CCH   20
#define LP    31
#define SIGCH 8420
#define SIGP  8448   // padded K; 8448 = 11*768, 768 = 12*64
#define NOUT  128
#define KSPLIT 11
#define KLEN  768    // per-split K: 12 chunks of BK=64

typedef _Float16 f16;
typedef _Float16 f16x8 __attribute__((ext_vector_type(8)));
typedef _Float16 f16x4 __attribute__((ext_vector_type(4)));
typedef _Float16 f16x2 __attribute__((ext_vector_type(2)));
typedef float    f32x4 __attribute__((ext_vector_type(4)));

// ---------------------------------------------------------------------------
// Kernel 1: fused augment (MFMA conv, weights built inline from w1) +
// signature-as-mini-GEMM (MFMA, operand-swapped so sig stores are f16x4 runs).
// Blocks 0..511: 4 batches, 1 wave/batch. Blocks 512..543: w_out->f16 convert.
//   S3[p][k] = sum_t U[t][p]*SufD[t][k] + E2[t][p]*d[t][k]
//   U[t][p=(i,j)] = (s1pre+0.5d)_i d_j,  E2 = (0.5 s1pre + d/6)_i d_j
//   SufD[t][k] = sum_{t'>t} d[t'][k];  s2[p] = sum_t U[t][p] (ones row 20 of V)
// Swapped mfma(V,UE) -> D[c][p]: lane col=p, rows=4 consecutive channels c.
// LDS 49.5 KB -> 3 blocks/CU.
// ---------------------------------------------------------------------------
__global__ __launch_bounds__(256, 3) void k_augsig(
    const float* __restrict__ x,  const float* __restrict__ w1, const float* __restrict__ b1,
    const float* __restrict__ w2, const float* __restrict__ b2,
    const float* __restrict__ w3, const float* __restrict__ b3,
    const float* __restrict__ w_out, f16* __restrict__ wh, f16* __restrict__ sig)
{
    if (blockIdx.x >= 512) {
        int t0 = (blockIdx.x - 512) * 256 + threadIdx.x;     // 8192 threads
        for (int chunk = t0; chunk < 128 * 1056; chunk += 8192) {
            int o  = chunk / 1056;
            int cw = chunk - o * 1056;
            int c0 = cw * 8;
            f16x8 v;
            if (c0 + 8 <= SIGCH) {
                const float* src = w_out + (size_t)o * SIGCH + c0;
                float4 a = *(const float4*)src;
                float4 b = *(const float4*)(src + 4);
                v = (f16x8){(f16)a.x,(f16)a.y,(f16)a.z,(f16)a.w,
                            (f16)b.x,(f16)b.y,(f16)b.z,(f16)b.w};
            } else {
#pragma unroll
                for (int e = 0; e < 8; ++e) {
                    int c = c0 + e;
                    v[e] = (c < SIGCH) ? (f16)w_out[(size_t)o * SIGCH + c] : (f16)0.f;
                }
            }
            *(f16x8*)(wh + (size_t)o * SIGP + c0) = v;
        }
        return;
    }

    // LDS pool 12388 floats = 49.55 KB:
    //  [0..9408)      per-batch sig scratch, f16 units: batch w at f16 off w*4704
    //                 dtr 0..800 | atr 800..1600 | etr 1600..2400 | V 2400..4704
    //                 early aliases: xs @0 (4272 f32), xp16/h1s @4272 (2304 f32)
    //  [9408..12032)  pprev (4 x 656 f32)
    //  [12032..12388) wsmall
    __shared__ float pool[12388];
    float* xs    = pool;
    f16*   xp16  = (f16*)(pool + 4272);
    float* h1s   = (float*)xp16;
    float* pprev = pool + 9408;
    float* wsmall= pool + 12032;
    float* w2s = wsmall;        float* b2s = wsmall + 256;
    float* w3s = wsmall + 272;  float* b3s = wsmall + 336;
    float* b1s = wsmall + 340;

    const int tid  = threadIdx.x;
    const int b0   = blockIdx.x * 4;
    const int lane = tid & 63;
    const int w    = tid >> 6;
    const int n16  = lane & 15;
    const int q4   = lane >> 4;

    // ---- inline conv-weight fragments (was k_prep); w1 is 38 KB, L1/L2-cached
    f16x8 wa[20];
#pragma unroll
    for (int g = 0; g < 20; ++g) {
#pragma unroll
        for (int j = 0; j < 8; ++j) {
            int kq = q4 * 8 + j;
            int kk = 2 * g + (kq >> 4);
            int c  = kq & 15;
            wa[g][j] = (c < D_INC) ? (f16)w1[n16 * 600 + c * 40 + kk] : (f16)0.f;
        }
    }

    for (int i = tid; i < 4 * 1050; i += 256) {
        int bl = i / 1050; int t = i - bl * 1050;
        xs[bl * 1068 + t] = x[(size_t)b0 * 1050 + i];
    }
    if (tid < 256) w2s[tid] = w2[tid];
    if (tid < 16)  b2s[tid] = b2[tid];
    if (tid < 64)  w3s[tid] = w3[tid];
    if (tid < 4)   b3s[tid] = b3[tid];
    if (tid < 16)  b1s[tid] = b1[tid];
    __syncthreads();

    // ---- build xp16: [bl][pos][c], c padded to 16 (c=15 -> 0)
    for (int r = tid; r < 280; r += 256) {
        int bl = r / 70; int pos = r - bl * 70;
        const float* src = xs + bl * 1068 + pos * 15;
        f16* dst = xp16 + bl * 1152 + pos * 16;
#pragma unroll
        for (int c = 0; c < 15; ++c) dst[c] = (f16)src[c];
        dst[15] = (f16)0.f;
    }
    __syncthreads();

    // ---- conv via MFMA
    f32x4 cacc[2];
#pragma unroll
    for (int tile = 0; tile < 2; ++tile) {
        const int pos0 = tile * 15;
        f32x4 acc = {0.f, 0.f, 0.f, 0.f};
#pragma unroll
        for (int g = 0; g < 20; ++g) {
            const f16x8 bf = *(const f16x8*)&xp16[w * 1152 +
                (pos0 + n16 + 2 * g + (q4 >> 1)) * 16 + (q4 & 1) * 8];
            acc = __builtin_amdgcn_mfma_f32_16x16x32_f16(wa[g], bf, acc, 0, 0, 0);
        }
        cacc[tile] = acc;
    }
    __syncthreads();            // xp16 reads done before h1s alias write

#pragma unroll
    for (int tile = 0; tile < 2; ++tile) {
        int pos = tile * 15 + n16;
#pragma unroll
        for (int r = 0; r < 4; ++r) {
            int h = q4 * 4 + r;
            h1s[(w * 31 + pos) * 17 + h] = fmaxf(cacc[tile][r] + b1s[h], 0.f);
        }
    }
    __syncthreads();

    // ---- small MLPs; write path rows into pprev (LDS)
    if (tid < 124) {
        const int bl2 = tid / 31;
        const int pos = tid - bl2 * 31;
        float hr[16];
#pragma unroll
        for (int c2 = 0; c2 < 16; ++c2) hr[c2] = h1s[tid * 17 + c2];
        float h2[16];
#pragma unroll
        for (int o = 0; o < 16; ++o) {
            float s = b2s[o];
#pragma unroll
            for (int c2 = 0; c2 < 16; ++c2) s += w2s[o * 16 + c2] * hr[c2];
            h2[o] = fmaxf(s, 0.f);
        }
        float h3[4];
#pragma unroll
        for (int f = 0; f < 4; ++f) {
            float s = b3s[f];
#pragma unroll
            for (int c2 = 0; c2 < 16; ++c2) s += w3s[f * 16 + c2] * h2[c2];
            h3[f] = s;
        }
        float* pr = pprev + bl2 * 656 + 20 + pos * 20;
#pragma unroll
        for (int d = 0; d < D_INC; ++d) pr[d] = xs[bl2 * 1068 + (pos + 39) * 15 + d];
        pr[15] = (float)pos * (1.0f / 30.0f);
#pragma unroll
        for (int f = 0; f < 4; ++f) pr[16 + f] = h3[f];
    } else {
        int z = tid - 124;
        if (z < 80) pprev[(z / 20) * 656 + (z % 20)] = 0.f;
    }
    __syncthreads();           // pprev complete; xs/xp16 dead -> scratch alias OK

    // ---- per-batch f16 scratch
    float* pp   = pprev + w * 656;
    f16*   scr  = (f16*)pool + w * 4704;   // 9408 B/batch, 16B-aligned
    f16*   dtr  = scr;                     // [c][t] stride 40 f16 (80 B)
    f16*   atr  = scr + 800;
    f16*   etr  = scr + 1600;
    f16*   Vb   = scr + 2400;              // [n<32][k<64] stride 72 f16 (144 B)

    // (a) transposed d / A / E (f32 math, f16 store)
    for (int e = lane; e < 620; e += 64) {
        int c = e / 31, t = e - c * 31;
        float p0 = pp[t * 20 + c];
        float d  = pp[(t + 1) * 20 + c] - p0;
        dtr[c * 40 + t] = (f16)d;
        atr[c * 40 + t] = (f16)(p0 + 0.5f * d);
        etr[c * 40 + t] = (f16)(0.5f * p0 + d * (1.0f / 6.0f));
    }
    if (lane < 20) {
        dtr[lane * 40 + 31] = (f16)0.f;
        atr[lane * 40 + 31] = (f16)0.f;
        etr[lane * 40 + 31] = (f16)0.f;
    }
    __syncthreads();

    // (b) V: rows 0..19 = [SufD | d]; row 20 = ones|0 (s2); rows 21..31 = 0
    if (lane < 20) {
        f16* vr = Vb + lane * 72;
        float s = 0.f;
        for (int t = 30; t >= 0; --t) {
            float dv = (float)dtr[lane * 40 + t];
            vr[t]      = (f16)s;
            vr[32 + t] = (f16)dv;
            s += dv;
        }
        vr[31] = (f16)0.f;
        vr[63] = (f16)0.f;
    } else if (lane == 20) {
        f16* vr = Vb + 20 * 72;
        for (int k = 0; k < 64; ++k) vr[k] = (k < 31) ? (f16)1.f : (f16)0.f;
    }
    for (int e = lane; e < 11 * 32; e += 64) {       // zero rows 21..31
        int row = 21 + (e >> 5);
        int kk  = (e & 31) * 2;
        *(f16x2*)(Vb + row * 72 + kk) = (f16x2){(f16)0.f, (f16)0.f};
    }
    __syncthreads();

    // hoisted V fragments (A-operand role): rows nt*16+n16, k-window kc*32
    f16x8 bf[2][2];
#pragma unroll
    for (int kc = 0; kc < 2; ++kc)
#pragma unroll
        for (int nt = 0; nt < 2; ++nt)
            bf[kc][nt] = *(const f16x8*)(Vb + (nt * 16 + n16) * 72 + kc * 32 + q4 * 8);

    const int b = b0 + w;
    f16* sg = sig + (size_t)b * SIGP;

    // m-loop: 25 tiles of 16 pairs; UE frags in registers (pk_mul f16)
    for (int mt = 0; mt < 25; ++mt) {
        const int p = mt * 16 + n16;                 // p < 400 always
        const int i = p / 20, j = p - i * 20;
        f16x8 av = *(const f16x8*)(atr + i * 40 + q4 * 8);
        f16x8 ev = *(const f16x8*)(etr + i * 40 + q4 * 8);
        f16x8 dv = *(const f16x8*)(dtr + j * 40 + q4 * 8);
        f16x8 uf = av * dv;
        f16x8 ef = ev * dv;

        f32x4 a0 = {0.f,0.f,0.f,0.f}, a1 = {0.f,0.f,0.f,0.f};
        a0 = __builtin_amdgcn_mfma_f32_16x16x32_f16(bf[0][0], uf, a0, 0, 0, 0);
        a0 = __builtin_amdgcn_mfma_f32_16x16x32_f16(bf[1][0], ef, a0, 0, 0, 0);
        a1 = __builtin_amdgcn_mfma_f32_16x16x32_f16(bf[0][1], uf, a1, 0, 0, 0);
        a1 = __builtin_amdgcn_mfma_f32_16x16x32_f16(bf[1][1], ef, a1, 0, 0, 0);

        // D[c][p]: lane col = p-in-tile (n16), rows = c = (tile16) + q4*4 + r
        f16x4 s0 = {(f16)a0[0], (f16)a0[1], (f16)a0[2], (f16)a0[3]};
        *(f16x4*)(sg + 420 + p * 20 + q4 * 4) = s0;          // channels q4*4..+3
        if (q4 == 0) {
            f16x4 s1v = {(f16)a1[0], (f16)a1[1], (f16)a1[2], (f16)a1[3]};
            *(f16x4*)(sg + 420 + p * 20 + 16) = s1v;         // channels 16..19
        } else if (q4 == 1) {
            sg[20 + p] = (f16)a1[0];                         // s2 (ones row 20)
        }
    }

    if (lane < 20) sg[lane] = (f16)pp[620 + lane];          // s1 = path[30]
    if (lane < 28) sg[SIGCH + lane] = (f16)0.f;             // zero K pad
}

// ---------------------------------------------------------------------------
// Kernel 2: fp16 MFMA GEMM, BM32/BN128/BK64, split-K 11 (12 iters of 64).
// ---------------------------------------------------------------------------
__global__ __launch_bounds__(256) void k_gemm(const f16* __restrict__ sigh,
                                              const f16* __restrict__ wh,
                                              float* __restrict__ z_part)
{
    __shared__ f16 As[2048];
    __shared__ f16 Bs[8192];
    const int tid = threadIdx.x;
    const int l   = tid & 63;
    const int wv  = tid >> 6;
    const int mt  = blockIdx.x / KSPLIT;
    const int s   = blockIdx.x - mt * KSPLIT;
    const int m0  = mt * 32;
    const int kb  = s * KLEN;

    const f32x4 z4 = {0.f, 0.f, 0.f, 0.f};
    f32x4 acc[2][2];
    acc[0][0] = z4; acc[0][1] = z4; acc[1][0] = z4; acc[1][1] = z4;

    const size_t gA = (size_t)(m0 + (tid & 31)) * SIGP + kb + (tid >> 5) * 8;
    size_t gB[4];
#pragma unroll
    for (int r = 0; r < 4; ++r) {
        int slot = r * 256 + tid;
        gB[r] = (size_t)(slot & 127) * SIGP + kb + (slot >> 7) * 8;
    }

    f16x8 aR = *(const f16x8*)(sigh + gA);
    f16x8 bR[4];
#pragma unroll
    for (int r = 0; r < 4; ++r) bR[r] = *(const f16x8*)(wh + gB[r]);

    const int kg   = l >> 4;
    const int mrow = l & 15;

    for (int ch = 0; ch < 12; ++ch) {
        *(f16x8*)&As[tid * 8] = aR;
#pragma unroll
        for (int r = 0; r < 4; ++r) *(f16x8*)&Bs[(r * 256 + tid) * 8] = bR[r];
        __syncthreads();

        if (ch < 11) {
            int koff = (ch + 1) * 64;
            aR = *(const f16x8*)(sigh + gA + koff);
#pragma unroll
            for (int r = 0; r < 4; ++r) bR[r] = *(const f16x8*)(wh + gB[r] + koff);
        }

#pragma unroll
        for (int kc = 0; kc < 2; ++kc) {
            f16x8 aF[2], bF[2];
#pragma unroll
            for (int m2 = 0; m2 < 2; ++m2)
                aF[m2] = *(const f16x8*)&As[((kc * 4 + kg) * 32 + m2 * 16 + mrow) * 8];
#pragma unroll
            for (int n2 = 0; n2 < 2; ++n2)
                bF[n2] = *(const f16x8*)&Bs[((kc * 4 + kg) * 128 + wv * 32 + n2 * 16 + mrow) * 8];
#pragma unroll
            for (int m2 = 0; m2 < 2; ++m2)
#pragma unroll
                for (int n2 = 0; n2 < 2; ++n2)
                    acc[m2][n2] = __builtin_amdgcn_mfma_f32_16x16x32_f16(aF[m2], bF[n2], acc[m2][n2], 0, 0, 0);
        }
        __syncthreads();
    }

#pragma unroll
    for (int m2 = 0; m2 < 2; ++m2) {
#pragma unroll
        for (int n2 = 0; n2 < 2; ++n2) {
            int n = wv * 32 + n2 * 16 + (l & 15);
#pragma unroll
            for (int r = 0; r < 4; ++r) {
                int m = m0 + m2 * 16 + (l >> 4) * 4 + r;
                z_part[((size_t)s * B_TOT + m) * NOUT + n] = acc[m2][n2][r];
            }
        }
    }
}

// ---------------------------------------------------------------------------
// Kernel 3: reduce 11 split-K partials, add bias, softplus on second half.
// ---------------------------------------------------------------------------
__global__ __launch_bounds__(256) void k_final(const float* __restrict__ z_part,
                                               const float* __restrict__ b_out,
                                               float* __restrict__ out)
{
    int idx = blockIdx.x * 256 + threadIdx.x;   // 2048*128
    int b = idx >> 7;
    int o = idx & 127;
    float z = b_out[o];
#pragma unroll
    for (int s = 0; s < KSPLIT; ++s) z += z_part[((size_t)s * B_TOT + b) * NOUT + o];
    if (o < 64) {
        out[(size_t)b * 64 + o] = z;
    } else {
        float sp = fmaxf(z, 0.f) + log1pf(expf(-fabsf(z)));
        out[131072 + (size_t)b * 64 + (o - 64)] = sp;
    }
}

// ---------------------------------------------------------------------------
extern "C" void kernel_launch(void* const* d_in, const int* in_sizes, int n_in,
                              void* d_out, int out_size, void* d_ws, size_t ws_size,
                              hipStream_t stream)
{
    const float* x     = (const float*)d_in[0];
    const float* w1    = (const float*)d_in[2];
    const float* b1    = (const float*)d_in[3];
    const float* w2    = (const float*)d_in[4];
    const float* b2    = (const float*)d_in[5];
    const float* w3    = (const float*)d_in[6];
    const float* b3    = (const float*)d_in[7];
    const float* w_out = (const float*)d_in[8];
    const float* b_out = (const float*)d_in[9];
    float* out = (float*)d_out;

    // float-unit offsets: N f16 elements occupy N/2 float units.
    float* ws    = (float*)d_ws;
    f16*   sigh  = (f16*)ws;                        // 2048*8448 f16 = 8,650,752 fu
    f16*   wh    = (f16*)(ws + 8650752);            // 128*8448 f16  =   540,672 fu
    float* zpart = ws + 9191424;                    // 11*2048*128   = 2,883,584 f
    // total 12,075,008 floats ~= 48.3 MB

    hipLaunchKernelGGL(k_augsig, dim3(544),  dim3(256), 0, stream,
                       x, w1, b1, w2, b2, w3, b3, w_out, wh, sigh);
    hipLaunchKernelGGL(k_gemm,   dim3(704),  dim3(256), 0, stream, sigh, wh, zpart);
    hipLaunchKernelGGL(k_final,  dim3(1024), dim3(256), 0, stream, zpart, b_out, out);
}

// Round 9
// 135.744 us; speedup vs baseline: 1.2174x; 1.2174x over previous
//
#include <hip/hip_runtime.h>
#include <math.h>

#define B_TOT 2048
#define D_INC 15
#define KW    40
#define CCH   20
#define LP    31
#define SIGCH 8420
#define SIGP  8448   // padded K; 8448 = 11*768, 768 = 12*64
#define NOUT  128
#define KSPLIT 11
#define KLEN  768    // per-split K: 12 chunks of BK=64

typedef _Float16 f16;
typedef _Float16 f16x8 __attribute__((ext_vector_type(8)));
typedef _Float16 f16x4 __attribute__((ext_vector_type(4)));
typedef _Float16 f16x2 __attribute__((ext_vector_type(2)));
typedef float    f32x4 __attribute__((ext_vector_type(4)));

// ---------------------------------------------------------------------------
// Kernel 0: prep conv weights into MFMA A-fragment layout (fp16).
// wA[g][lane][j]: A[m=h][k], h=lane&15, kq=(lane>>4)*8+j, kk=2g+(kq>>4),
// c=kq&15 (c==15 -> 0 pad). Scattered reads live HERE (1 block, ~2 us),
// so k_augsig's 2048 waves load fragments coalesced (b128). [r8 post-mortem]
// ---------------------------------------------------------------------------
__global__ __launch_bounds__(256) void k_prep(const float* __restrict__ w1,
                                              f16* __restrict__ wA)
{
    const int ln = threadIdx.x & 63;
    const int wv = threadIdx.x >> 6;
    const int h  = ln & 15;
    const int q4 = ln >> 4;
    for (int gi = 0; gi < 5; ++gi) {
        int g = wv * 5 + gi;
        f16x8 v;
#pragma unroll
        for (int j = 0; j < 8; ++j) {
            int kq = q4 * 8 + j;
            int kk = 2 * g + (kq >> 4);
            int c  = kq & 15;
            v[j] = (c < D_INC) ? (f16)w1[h * 600 + c * 40 + kk] : (f16)0.f;
        }
        *(f16x8*)(wA + g * 512 + ln * 8) = v;
    }
}

// ---------------------------------------------------------------------------
// Kernel 1: fused augment (MFMA conv) + signature-as-mini-GEMM (MFMA,
// operand-swapped so sig stores are f16x4 channel runs).
// Blocks 0..511: 4 batches, 1 wave/batch. Blocks 512..543: w_out->f16 convert.
//   S3[p][k] = sum_t U[t][p]*SufD[t][k] + E2[t][p]*d[t][k]
//   U[t][p=(i,j)] = (s1pre+0.5d)_i d_j,  E2 = (0.5 s1pre + d/6)_i d_j
//   SufD[t][k] = sum_{t'>t} d[t'][k];  s2[p] = sum_t U[t][p] (ones row 20 of V)
// Swapped mfma(V,UE) -> D[c][p]: lane col=p, rows=4 consecutive channels c.
// LDS 49.5 KB -> 3 blocks/CU.
// ---------------------------------------------------------------------------
__global__ __launch_bounds__(256, 3) void k_augsig(
    const float* __restrict__ x,  const f16* __restrict__ wA, const float* __restrict__ b1,
    const float* __restrict__ w2, const float* __restrict__ b2,
    const float* __restrict__ w3, const float* __restrict__ b3,
    const float* __restrict__ w_out, f16* __restrict__ wh, f16* __restrict__ sig)
{
    if (blockIdx.x >= 512) {
        int t0 = (blockIdx.x - 512) * 256 + threadIdx.x;     // 8192 threads
        for (int chunk = t0; chunk < 128 * 1056; chunk += 8192) {
            int o  = chunk / 1056;
            int cw = chunk - o * 1056;
            int c0 = cw * 8;
            f16x8 v;
            if (c0 + 8 <= SIGCH) {
                const float* src = w_out + (size_t)o * SIGCH + c0;
                float4 a = *(const float4*)src;
                float4 b = *(const float4*)(src + 4);
                v = (f16x8){(f16)a.x,(f16)a.y,(f16)a.z,(f16)a.w,
                            (f16)b.x,(f16)b.y,(f16)b.z,(f16)b.w};
            } else {
#pragma unroll
                for (int e = 0; e < 8; ++e) {
                    int c = c0 + e;
                    v[e] = (c < SIGCH) ? (f16)w_out[(size_t)o * SIGCH + c] : (f16)0.f;
                }
            }
            *(f16x8*)(wh + (size_t)o * SIGP + c0) = v;
        }
        return;
    }

    // LDS pool 12388 floats = 49.55 KB:
    //  [0..9408)      per-batch sig scratch, f16 units: batch w at f16 off w*4704
    //                 dtr 0..800 | atr 800..1600 | etr 1600..2400 | V 2400..4704
    //                 early aliases: xs @0 (4272 f32), xp16/h1s @4272 (2304 f32)
    //  [9408..12032)  pprev (4 x 656 f32)
    //  [12032..12388) wsmall
    __shared__ float pool[12388];
    float* xs    = pool;
    f16*   xp16  = (f16*)(pool + 4272);
    float* h1s   = (float*)xp16;
    float* pprev = pool + 9408;
    float* wsmall= pool + 12032;
    float* w2s = wsmall;        float* b2s = wsmall + 256;
    float* w3s = wsmall + 272;  float* b3s = wsmall + 336;
    float* b1s = wsmall + 340;

    const int tid  = threadIdx.x;
    const int b0   = blockIdx.x * 4;
    const int lane = tid & 63;
    const int w    = tid >> 6;
    const int n16  = lane & 15;
    const int q4   = lane >> 4;

    for (int i = tid; i < 4 * 1050; i += 256) {
        int bl = i / 1050; int t = i - bl * 1050;
        xs[bl * 1068 + t] = x[(size_t)b0 * 1050 + i];
    }
    if (tid < 256) w2s[tid] = w2[tid];
    if (tid < 16)  b2s[tid] = b2[tid];
    if (tid < 64)  w3s[tid] = w3[tid];
    if (tid < 4)   b3s[tid] = b3[tid];
    if (tid < 16)  b1s[tid] = b1[tid];

    // coalesced conv-weight fragments (b128 per lane, L2-resident after k_prep)
    f16x8 wa[20];
#pragma unroll
    for (int g = 0; g < 20; ++g) wa[g] = *(const f16x8*)(wA + g * 512 + lane * 8);
    __syncthreads();

    // ---- build xp16: [bl][pos][c], c padded to 16 (c=15 -> 0)
    for (int r = tid; r < 280; r += 256) {
        int bl = r / 70; int pos = r - bl * 70;
        const float* src = xs + bl * 1068 + pos * 15;
        f16* dst = xp16 + bl * 1152 + pos * 16;
#pragma unroll
        for (int c = 0; c < 15; ++c) dst[c] = (f16)src[c];
        dst[15] = (f16)0.f;
    }
    __syncthreads();

    // ---- conv via MFMA
    f32x4 cacc[2];
#pragma unroll
    for (int tile = 0; tile < 2; ++tile) {
        const int pos0 = tile * 15;
        f32x4 acc = {0.f, 0.f, 0.f, 0.f};
#pragma unroll
        for (int g = 0; g < 20; ++g) {
            const f16x8 bf = *(const f16x8*)&xp16[w * 1152 +
                (pos0 + n16 + 2 * g + (q4 >> 1)) * 16 + (q4 & 1) * 8];
            acc = __builtin_amdgcn_mfma_f32_16x16x32_f16(wa[g], bf, acc, 0, 0, 0);
        }
        cacc[tile] = acc;
    }
    __syncthreads();            // xp16 reads done before h1s alias write

#pragma unroll
    for (int tile = 0; tile < 2; ++tile) {
        int pos = tile * 15 + n16;
#pragma unroll
        for (int r = 0; r < 4; ++r) {
            int h = q4 * 4 + r;
            h1s[(w * 31 + pos) * 17 + h] = fmaxf(cacc[tile][r] + b1s[h], 0.f);
        }
    }
    __syncthreads();

    // ---- small MLPs; write path rows into pprev (LDS)
    if (tid < 124) {
        const int bl2 = tid / 31;
        const int pos = tid - bl2 * 31;
        float hr[16];
#pragma unroll
        for (int c2 = 0; c2 < 16; ++c2) hr[c2] = h1s[tid * 17 + c2];
        float h2[16];
#pragma unroll
        for (int o = 0; o < 16; ++o) {
            float s = b2s[o];
#pragma unroll
            for (int c2 = 0; c2 < 16; ++c2) s += w2s[o * 16 + c2] * hr[c2];
            h2[o] = fmaxf(s, 0.f);
        }
        float h3[4];
#pragma unroll
        for (int f = 0; f < 4; ++f) {
            float s = b3s[f];
#pragma unroll
            for (int c2 = 0; c2 < 16; ++c2) s += w3s[f * 16 + c2] * h2[c2];
            h3[f] = s;
        }
        float* pr = pprev + bl2 * 656 + 20 + pos * 20;
#pragma unroll
        for (int d = 0; d < D_INC; ++d) pr[d] = xs[bl2 * 1068 + (pos + 39) * 15 + d];
        pr[15] = (float)pos * (1.0f / 30.0f);
#pragma unroll
        for (int f = 0; f < 4; ++f) pr[16 + f] = h3[f];
    } else {
        int z = tid - 124;
        if (z < 80) pprev[(z / 20) * 656 + (z % 20)] = 0.f;
    }
    __syncthreads();           // pprev complete; xs/xp16 dead -> scratch alias OK

    // ---- per-batch f16 scratch
    float* pp   = pprev + w * 656;
    f16*   scr  = (f16*)pool + w * 4704;   // 9408 B/batch, 16B-aligned
    f16*   dtr  = scr;                     // [c][t] stride 40 f16 (80 B)
    f16*   atr  = scr + 800;
    f16*   etr  = scr + 1600;
    f16*   Vb   = scr + 2400;              // [n<32][k<64] stride 72 f16 (144 B)

    // (a) transposed d / A / E (f32 math, f16 store)
    for (int e = lane; e < 620; e += 64) {
        int c = e / 31, t = e - c * 31;
        float p0 = pp[t * 20 + c];
        float d  = pp[(t + 1) * 20 + c] - p0;
        dtr[c * 40 + t] = (f16)d;
        atr[c * 40 + t] = (f16)(p0 + 0.5f * d);
        etr[c * 40 + t] = (f16)(0.5f * p0 + d * (1.0f / 6.0f));
    }
    if (lane < 20) {
        dtr[lane * 40 + 31] = (f16)0.f;
        atr[lane * 40 + 31] = (f16)0.f;
        etr[lane * 40 + 31] = (f16)0.f;
    }
    __syncthreads();

    // (b) V: rows 0..19 = [SufD | d]; row 20 = ones|0 (s2); rows 21..31 = 0
    if (lane < 20) {
        f16* vr = Vb + lane * 72;
        float s = 0.f;
        for (int t = 30; t >= 0; --t) {
            float dv = (float)dtr[lane * 40 + t];
            vr[t]      = (f16)s;
            vr[32 + t] = (f16)dv;
            s += dv;
        }
        vr[31] = (f16)0.f;
        vr[63] = (f16)0.f;
    } else if (lane == 20) {
        f16* vr = Vb + 20 * 72;
        for (int k = 0; k < 64; ++k) vr[k] = (k < 31) ? (f16)1.f : (f16)0.f;
    }
    for (int e = lane; e < 11 * 32; e += 64) {       // zero rows 21..31
        int row = 21 + (e >> 5);
        int kk  = (e & 31) * 2;
        *(f16x2*)(Vb + row * 72 + kk) = (f16x2){(f16)0.f, (f16)0.f};
    }
    __syncthreads();

    // hoisted V fragments (A-operand role): rows nt*16+n16, k-window kc*32
    f16x8 bf[2][2];
#pragma unroll
    for (int kc = 0; kc < 2; ++kc)
#pragma unroll
        for (int nt = 0; nt < 2; ++nt)
            bf[kc][nt] = *(const f16x8*)(Vb + (nt * 16 + n16) * 72 + kc * 32 + q4 * 8);

    const int b = b0 + w;
    f16* sg = sig + (size_t)b * SIGP;

    // m-loop: 25 tiles of 16 pairs; UE frags in registers (pk_mul f16)
    for (int mt = 0; mt < 25; ++mt) {
        const int p = mt * 16 + n16;                 // p < 400 always
        const int i = p / 20, j = p - i * 20;
        f16x8 av = *(const f16x8*)(atr + i * 40 + q4 * 8);
        f16x8 ev = *(const f16x8*)(etr + i * 40 + q4 * 8);
        f16x8 dv = *(const f16x8*)(dtr + j * 40 + q4 * 8);
        f16x8 uf = av * dv;
        f16x8 ef = ev * dv;

        f32x4 a0 = {0.f,0.f,0.f,0.f}, a1 = {0.f,0.f,0.f,0.f};
        a0 = __builtin_amdgcn_mfma_f32_16x16x32_f16(bf[0][0], uf, a0, 0, 0, 0);
        a0 = __builtin_amdgcn_mfma_f32_16x16x32_f16(bf[1][0], ef, a0, 0, 0, 0);
        a1 = __builtin_amdgcn_mfma_f32_16x16x32_f16(bf[0][1], uf, a1, 0, 0, 0);
        a1 = __builtin_amdgcn_mfma_f32_16x16x32_f16(bf[1][1], ef, a1, 0, 0, 0);

        // D[c][p]: lane col = p-in-tile (n16), rows = c = (tile16) + q4*4 + r
        f16x4 s0 = {(f16)a0[0], (f16)a0[1], (f16)a0[2], (f16)a0[3]};
        *(f16x4*)(sg + 420 + p * 20 + q4 * 4) = s0;          // channels q4*4..+3
        if (q4 == 0) {
            f16x4 s1v = {(f16)a1[0], (f16)a1[1], (f16)a1[2], (f16)a1[3]};
            *(f16x4*)(sg + 420 + p * 20 + 16) = s1v;         // channels 16..19
        } else if (q4 == 1) {
            sg[20 + p] = (f16)a1[0];                         // s2 (ones row 20)
        }
    }

    if (lane < 20) sg[lane] = (f16)pp[620 + lane];          // s1 = path[30]
    if (lane < 28) sg[SIGCH + lane] = (f16)0.f;             // zero K pad
}

// ---------------------------------------------------------------------------
// Kernel 2: fp16 MFMA GEMM, BM32/BN128/BK64, split-K 11 (12 iters of 64).
// ---------------------------------------------------------------------------
__global__ __launch_bounds__(256) void k_gemm(const f16* __restrict__ sigh,
                                              const f16* __restrict__ wh,
                                              float* __restrict__ z_part)
{
    __shared__ f16 As[2048];
    __shared__ f16 Bs[8192];
    const int tid = threadIdx.x;
    const int l   = tid & 63;
    const int wv  = tid >> 6;
    const int mt  = blockIdx.x / KSPLIT;
    const int s   = blockIdx.x - mt * KSPLIT;
    const int m0  = mt * 32;
    const int kb  = s * KLEN;

    const f32x4 z4 = {0.f, 0.f, 0.f, 0.f};
    f32x4 acc[2][2];
    acc[0][0] = z4; acc[0][1] = z4; acc[1][0] = z4; acc[1][1] = z4;

    const size_t gA = (size_t)(m0 + (tid & 31)) * SIGP + kb + (tid >> 5) * 8;
    size_t gB[4];
#pragma unroll
    for (int r = 0; r < 4; ++r) {
        int slot = r * 256 + tid;
        gB[r] = (size_t)(slot & 127) * SIGP + kb + (slot >> 7) * 8;
    }

    f16x8 aR = *(const f16x8*)(sigh + gA);
    f16x8 bR[4];
#pragma unroll
    for (int r = 0; r < 4; ++r) bR[r] = *(const f16x8*)(wh + gB[r]);

    const int kg   = l >> 4;
    const int mrow = l & 15;

    for (int ch = 0; ch < 12; ++ch) {
        *(f16x8*)&As[tid * 8] = aR;
#pragma unroll
        for (int r = 0; r < 4; ++r) *(f16x8*)&Bs[(r * 256 + tid) * 8] = bR[r];
        __syncthreads();

        if (ch < 11) {
            int koff = (ch + 1) * 64;
            aR = *(const f16x8*)(sigh + gA + koff);
#pragma unroll
            for (int r = 0; r < 4; ++r) bR[r] = *(const f16x8*)(wh + gB[r] + koff);
        }

#pragma unroll
        for (int kc = 0; kc < 2; ++kc) {
            f16x8 aF[2], bF[2];
#pragma unroll
            for (int m2 = 0; m2 < 2; ++m2)
                aF[m2] = *(const f16x8*)&As[((kc * 4 + kg) * 32 + m2 * 16 + mrow) * 8];
#pragma unroll
            for (int n2 = 0; n2 < 2; ++n2)
                bF[n2] = *(const f16x8*)&Bs[((kc * 4 + kg) * 128 + wv * 32 + n2 * 16 + mrow) * 8];
#pragma unroll
            for (int m2 = 0; m2 < 2; ++m2)
#pragma unroll
                for (int n2 = 0; n2 < 2; ++n2)
                    acc[m2][n2] = __builtin_amdgcn_mfma_f32_16x16x32_f16(aF[m2], bF[n2], acc[m2][n2], 0, 0, 0);
        }
        __syncthreads();
    }

#pragma unroll
    for (int m2 = 0; m2 < 2; ++m2) {
#pragma unroll
        for (int n2 = 0; n2 < 2; ++n2) {
            int n = wv * 32 + n2 * 16 + (l & 15);
#pragma unroll
            for (int r = 0; r < 4; ++r) {
                int m = m0 + m2 * 16 + (l >> 4) * 4 + r;
                z_part[((size_t)s * B_TOT + m) * NOUT + n] = acc[m2][n2][r];
            }
        }
    }
}

// ---------------------------------------------------------------------------
// Kernel 3: reduce 11 split-K partials, add bias, softplus on second half.
// ---------------------------------------------------------------------------
__global__ __launch_bounds__(256) void k_final(const float* __restrict__ z_part,
                                               const float* __restrict__ b_out,
                                               float* __restrict__ out)
{
    int idx = blockIdx.x * 256 + threadIdx.x;   // 2048*128
    int b = idx >> 7;
    int o = idx & 127;
    float z = b_out[o];
#pragma unroll
    for (int s = 0; s < KSPLIT; ++s) z += z_part[((size_t)s * B_TOT + b) * NOUT + o];
    if (o < 64) {
        out[(size_t)b * 64 + o] = z;
    } else {
        float sp = fmaxf(z, 0.f) + log1pf(expf(-fabsf(z)));
        out[131072 + (size_t)b * 64 + (o - 64)] = sp;
    }
}

// ---------------------------------------------------------------------------
extern "C" void kernel_launch(void* const* d_in, const int* in_sizes, int n_in,
                              void* d_out, int out_size, void* d_ws, size_t ws_size,
                              hipStream_t stream)
{
    const float* x     = (const float*)d_in[0];
    const float* w1    = (const float*)d_in[2];
    const float* b1    = (const float*)d_in[3];
    const float* w2    = (const float*)d_in[4];
    const float* b2    = (const float*)d_in[5];
    const float* w3    = (const float*)d_in[6];
    const float* b3    = (const float*)d_in[7];
    const float* w_out = (const float*)d_in[8];
    const float* b_out = (const float*)d_in[9];
    float* out = (float*)d_out;

    // float-unit offsets: N f16 elements occupy N/2 float units.
    float* ws    = (float*)d_ws;
    f16*   sigh  = (f16*)ws;                        // 2048*8448 f16 = 8,650,752 fu
    f16*   wh    = (f16*)(ws + 8650752);            // 128*8448 f16  =   540,672 fu
    f16*   wA    = (f16*)(ws + 9191424);            // 10,240 f16    =     5,120 fu
    float* zpart = ws + 9196544;                    // 11*2048*128   = 2,883,584 f
    // total 12,080,128 floats ~= 48.3 MB

    hipLaunchKernelGGL(k_prep,   dim3(1),    dim3(256), 0, stream, w1, wA);
    hipLaunchKernelGGL(k_augsig, dim3(544),  dim3(256), 0, stream,
                       x, wA, b1, w2, b2, w3, b3, w_out, wh, sigh);
    hipLaunchKernelGGL(k_gemm,   dim3(704),  dim3(256), 0, stream, sigh, wh, zpart);
    hipLaunchKernelGGL(k_final,  dim3(1024), dim3(256), 0, stream, zpart, b_out, out);
}